// Round 10
// baseline (87.848 us; speedup 1.0000x reference)
//
#include <hip/hip_runtime.h>
#include <hip/hip_bf16.h>
#include <math.h>

typedef __bf16 bf16_t;
typedef __bf16 bf16x8 __attribute__((ext_vector_type(8)));
typedef float f32x4 __attribute__((ext_vector_type(4)));

#define N2 4096
#define NHALF 2048
#define DIM 512
#define TEMP_INV 2.0f   // 1/TEMPERATURE

// ---------------------------------------------------------------------------
// Kernel 1 (prep, slimmed — r7-verified): one wave per row-PAIR (i, i+N).
// Row norms + bf16 normalized rows only. Diagonal exclusion and positive
// logits are handled exactly in the GEMM epilogue. Zeroes rowsum slice.
// ---------------------------------------------------------------------------
__global__ __launch_bounds__(256) void k_prep(const float* __restrict__ x,
                                              bf16_t* __restrict__ xn,
                                              float* __restrict__ rowsum) {
    const int pair = blockIdx.x * 4 + (threadIdx.x >> 6);   // 0..2047
    const int lane = threadIdx.x & 63;
    const int rowi = pair;
    const int rowp = pair + NHALF;

    const float4* xi = reinterpret_cast<const float4*>(x + (size_t)rowi * DIM);
    const float4* xp = reinterpret_cast<const float4*>(x + (size_t)rowp * DIM);
    float4 a0 = xi[lane * 2], a1 = xi[lane * 2 + 1];
    float4 b0 = xp[lane * 2], b1 = xp[lane * 2 + 1];

    float ssi = a0.x*a0.x + a0.y*a0.y + a0.z*a0.z + a0.w*a0.w
              + a1.x*a1.x + a1.y*a1.y + a1.z*a1.z + a1.w*a1.w;
    float ssp = b0.x*b0.x + b0.y*b0.y + b0.z*b0.z + b0.w*b0.w
              + b1.x*b1.x + b1.y*b1.y + b1.z*b1.z + b1.w*b1.w;
#pragma unroll
    for (int off = 32; off; off >>= 1) {
        ssi += __shfl_xor(ssi, off, 64);
        ssp += __shfl_xor(ssp, off, 64);
    }
    const float sci = 1.0f / fmaxf(sqrtf(ssi), 1e-8f);
    const float scp = 1.0f / fmaxf(sqrtf(ssp), 1e-8f);

    float va[8] = {a0.x, a0.y, a0.z, a0.w, a1.x, a1.y, a1.z, a1.w};
    float vb[8] = {b0.x, b0.y, b0.z, b0.w, b1.x, b1.y, b1.z, b1.w};
    bf16x8 oi, op;
#pragma unroll
    for (int t = 0; t < 8; ++t) {
        oi[t] = (bf16_t)(va[t] * sci);
        op[t] = (bf16_t)(vb[t] * scp);
    }
    *reinterpret_cast<bf16x8*>(xn + (size_t)rowi * DIM + lane * 8) = oi;
    *reinterpret_cast<bf16x8*>(xn + (size_t)rowp * DIM + lane * 8) = op;

    // zero rowsum (8 entries per block covers 4096 over 512 blocks)
    if (threadIdx.x < 8) rowsum[blockIdx.x * 8 + threadIdx.x] = 0.0f;
}

// ---------------------------------------------------------------------------
// Kernel 2: symmetric sim-GEMM, upper-triangle blocks of 64x64 tiles:
// triangle(64) = 2080 blocks = 8.1/CU  <-- the TLP lever.
// All 2-blocks/CU variants (r1..r9) plateaued at simgemm ~20us with
// Occupancy ~13% / MfmaUtil ~6% (latency-bound). 64x64 tiles x 4 waves
// (each one 32x32, acc = 16 VGPR) at 33KB LDS -> 4 blocks/CU resident,
// 16 waves/CU: 4 independent block pipelines interleave their stall
// windows. LDS rows stay 64B -> the r4/r7 PMC-verified conflict-free
// XOR swizzle carries over unchanged.
// Quad-buffer, 2-deep prefetch: prologue stages tiles 0,1,2; iter kt
// stages kt+3; waits vmcnt(4)/(2)/(0) (2 loads per tile per thread).
// Epilogue masks (exact, absmax 0 in r8/r9): diag-exclusion on bm==bn,
// positive logits on bn==bm+32 (64-row panels: i <-> i+2048).
// ---------------------------------------------------------------------------
__device__ __forceinline__ void load_lds16(const bf16_t* g, bf16_t* l) {
    __builtin_amdgcn_global_load_lds(
        (const __attribute__((address_space(1))) unsigned int*)g,
        (__attribute__((address_space(3))) unsigned int*)l,
        16, 0, 0);
}

__global__ __launch_bounds__(256) void k_simgemm(const bf16_t* __restrict__ xn,
                                                 float* __restrict__ rowsum,
                                                 float* __restrict__ pos) {
    __shared__ bf16_t As[4][64 * 32];   // 4 x 4KB
    __shared__ bf16_t Bs[4][64 * 32];   // 4 x 4KB
    __shared__ float  rpA[64];
    __shared__ float  rpB[64];

    // XCD-chunked swizzle (bijective: 2080 = 8 x 260), then unrank (bm<=bn)
    const int t = (blockIdx.x & 7) * 260 + (blockIdx.x >> 3);
    int bn = (int)((sqrtf(8.0f * (float)t + 1.0f) - 1.0f) * 0.5f);
    while ((bn * (bn + 1)) / 2 > t) --bn;
    while (((bn + 1) * (bn + 2)) / 2 <= t) ++bn;
    const int bm = t - (bn * (bn + 1)) / 2;
    const bool diagb = (bm == bn);

    const int tid  = threadIdx.x;
    const int lane = tid & 63;
    const int wid  = tid >> 6;
    const int wr   = wid >> 1;     // 0..1 (M half: 32 rows)
    const int wc   = wid & 1;      // 0..1 (N half: 32 cols)
    const int q    = lane >> 4;
    const int l15  = lane & 15;

    if (tid < 64) rpA[tid] = 0.0f;
    else if (tid < 128) rpB[tid - 64] = 0.0f;

    // Staging: one K-tile = 64 rows x 32 cols bf16 = 4KB = 256 thr x 16B.
    // thread t -> dest row t>>2, dest slot t&3 (LDS linear, tid*16B);
    // GLOBAL slot XOR-swizzled: (t&3)^((t>>3)&3)  [same involution as r4].
    const int slot_g = (tid & 3) ^ ((tid >> 3) & 3);
    const bf16_t* gA = xn + (size_t)(bm * 64 + (tid >> 2)) * DIM + slot_g * 8;
    const bf16_t* gB = xn + (size_t)(bn * 64 + (tid >> 2)) * DIM + slot_g * 8;

    // fragment-read swizzle: slot_r = q ^ ((row>>1)&3), row = base16+l15.
    const int rsw  = (q ^ ((l15 >> 1) & 3)) * 8;
    const int arow = (wr * 32 + l15) * 32 + rsw;   // + mt*512
    const int brow = (wc * 32 + l15) * 32 + rsw;   // + nt*512

    f32x4 acc[2][2] = {};

    // prologue: stage K-tiles 0,1,2 (6 loads outstanding)
#pragma unroll
    for (int p = 0; p < 3; ++p) {
        load_lds16(gA + p * 32, &As[p][tid * 8]);
        load_lds16(gB + p * 32, &Bs[p][tid * 8]);
    }

#pragma unroll
    for (int kt = 0; kt < 16; ++kt) {
        // retire tile kt's loads; keep kt+1 (and kt+2 if staged) in flight
        if (kt < 14)       asm volatile("s_waitcnt vmcnt(4)" ::: "memory");
        else if (kt == 14) asm volatile("s_waitcnt vmcnt(2)" ::: "memory");
        else               asm volatile("s_waitcnt vmcnt(0)" ::: "memory");
        __builtin_amdgcn_s_barrier();      // tile kt resident for all waves;
                                           // all waves' kt-1 reads retired
        __builtin_amdgcn_sched_barrier(0); // pin: nothing floats above

        if (kt + 3 < 16) {                 // stage tile kt+3 (2-step cover)
            const int nb = (kt + 3) & 3;   // == (kt-1)&3, safe per barrier
            load_lds16(gA + (kt + 3) * 32, &As[nb][tid * 8]);
            load_lds16(gB + (kt + 3) * 32, &Bs[nb][tid * 8]);
        }

        const int cb = kt & 3;             // compile-time after unroll
        bf16x8 af[2], bv[2];
#pragma unroll
        for (int mt = 0; mt < 2; ++mt)
            af[mt] = *reinterpret_cast<const bf16x8*>(&As[cb][arow + mt * 512]);
#pragma unroll
        for (int nt = 0; nt < 2; ++nt)
            bv[nt] = *reinterpret_cast<const bf16x8*>(&Bs[cb][brow + nt * 512]);
#pragma unroll
        for (int mt = 0; mt < 2; ++mt)
#pragma unroll
            for (int nt = 0; nt < 2; ++nt)
                acc[mt][nt] = __builtin_amdgcn_mfma_f32_16x16x32_bf16(
                    af[mt], bv[nt], acc[mt][nt], 0, 0, 0);
    }

    // Epilogue. C/D: lr = wr*32+mt*16+q*4+r, lc = wc*32+nt*16+l15.
    const bool dmask = diagb && (wr == wc);           // true diagonal here
    const bool pmask = (bn == bm + 32) && (wr == wc); // sim[i,i+N] here
    float colacc[2] = {0.0f, 0.0f};
#pragma unroll
    for (int mt = 0; mt < 2; ++mt) {
        float rowp[4] = {0.0f, 0.0f, 0.0f, 0.0f};
#pragma unroll
        for (int nt = 0; nt < 2; ++nt)
#pragma unroll
            for (int r = 0; r < 4; ++r) {
                float e = __expf(TEMP_INV * acc[mt][nt][r]);
                if (mt == nt) {            // compile-time: 2 tile-pairs
                    const bool hit = (l15 == q * 4 + r);
                    if (dmask && hit) e = 0.0f;   // exclude j==i from lse
                    if (pmask && hit) {           // extract positive logit
                        const float pv = TEMP_INV * acc[mt][nt][r];
                        const int gr = bm * 64 + wr * 32 + mt * 16 + q * 4 + r;
                        pos[gr] = pv;             // unique writer per row:
                        pos[gr + NHALF] = pv;     // plain stores suffice
                    }
                }
                rowp[r] += e;
                colacc[nt] += e;
            }
#pragma unroll
        for (int r = 0; r < 4; ++r) {
            float p = rowp[r];
            p += __shfl_xor(p, 1, 64);
            p += __shfl_xor(p, 2, 64);
            p += __shfl_xor(p, 4, 64);
            p += __shfl_xor(p, 8, 64);
            if (l15 == 0) atomicAdd(&rpA[wr * 32 + mt * 16 + q * 4 + r], p);
        }
    }
    if (!diagb) {
#pragma unroll
        for (int nt = 0; nt < 2; ++nt) {
            float c = colacc[nt];
            c += __shfl_xor(c, 16, 64);
            c += __shfl_xor(c, 32, 64);
            if (q == 0) atomicAdd(&rpB[wc * 32 + nt * 16 + l15], c);
        }
    }
    __syncthreads();
    if (tid < 64) {
        atomicAdd(&rowsum[bm * 64 + tid], rpA[tid]);
    } else if (tid < 128 && !diagb) {
        atomicAdd(&rowsum[bn * 64 + (tid - 64)], rpB[tid - 64]);
    }
}

// ---------------------------------------------------------------------------
// Kernel 3: loss = mean_i( log(S_i) - pos_i )   (diag already excluded)
// float4-vectorized single block; 2 input streams.
// ---------------------------------------------------------------------------
__global__ __launch_bounds__(256) void k_finalize(const float* __restrict__ rowsum,
                                                  const float* __restrict__ pos,
                                                  float* __restrict__ out) {
    __shared__ float red[256];
    const float4* rs4 = reinterpret_cast<const float4*>(rowsum);
    const float4* ps4 = reinterpret_cast<const float4*>(pos);
    float s = 0.0f;
#pragma unroll
    for (int it = 0; it < 4; ++it) {
        const int i = it * 256 + threadIdx.x;   // 1024 float4 = 4096 floats
        float4 r = rs4[i];
        float4 p = ps4[i];
        s += __logf(r.x) - p.x;
        s += __logf(r.y) - p.y;
        s += __logf(r.z) - p.z;
        s += __logf(r.w) - p.w;
    }
    red[threadIdx.x] = s;
    __syncthreads();
    for (int st = 128; st; st >>= 1) {
        if (threadIdx.x < st) red[threadIdx.x] += red[threadIdx.x + st];
        __syncthreads();
    }
    if (threadIdx.x == 0) out[0] = red[0] / (float)N2;
}

// ---------------------------------------------------------------------------
extern "C" void kernel_launch(void* const* d_in, const int* in_sizes, int n_in,
                              void* d_out, int out_size, void* d_ws, size_t ws_size,
                              hipStream_t stream) {
    (void)in_sizes; (void)n_in; (void)out_size; (void)ws_size;
    const float* x = (const float*)d_in[0];
    float* out = (float*)d_out;

    char* ws = (char*)d_ws;
    bf16_t* xn     = (bf16_t*)ws;                          // 4 MB
    float*  rowsum = (float*)(ws + (size_t)N2 * DIM * 2);  // 16 KB
    float*  pos    = rowsum + N2;                          // 16 KB

    k_prep<<<512, 256, 0, stream>>>(x, xn, rowsum);
    k_simgemm<<<2080, 256, 0, stream>>>(xn, rowsum, pos);
    k_finalize<<<1, 256, 0, stream>>>(rowsum, pos, out);
}

// Round 11
// 79.223 us; speedup vs baseline: 1.1089x; 1.1089x over previous
//
#include <hip/hip_runtime.h>
#include <hip/hip_bf16.h>
#include <math.h>

typedef __bf16 bf16_t;
typedef __bf16 bf16x8 __attribute__((ext_vector_type(8)));
typedef float f32x4 __attribute__((ext_vector_type(4)));

#define N2 4096
#define NHALF 2048
#define DIM 512
#define TEMP_INV 2.0f   // 1/TEMPERATURE

// ---------------------------------------------------------------------------
// Kernel 1 (fused prep): one wave per row-PAIR (i, i+N). Loads both fp32 rows,
// computes norms + cross-dot, writes both bf16 rows, pos[i]=pos[p] (symmetric),
// diag per row from the bf16-rounded values (matches what the GEMM will sum),
// and zeroes this block's slice of rowsum.
// ---------------------------------------------------------------------------
__global__ __launch_bounds__(256) void k_prep(const float* __restrict__ x,
                                              bf16_t* __restrict__ xn,
                                              float* __restrict__ pos,
                                              float* __restrict__ diag,
                                              float* __restrict__ rowsum) {
    const int pair = blockIdx.x * 4 + (threadIdx.x >> 6);   // 0..2047
    const int lane = threadIdx.x & 63;
    const int rowi = pair;
    const int rowp = pair + NHALF;

    const float4* xi = reinterpret_cast<const float4*>(x + (size_t)rowi * DIM);
    const float4* xp = reinterpret_cast<const float4*>(x + (size_t)rowp * DIM);
    float4 a0 = xi[lane * 2], a1 = xi[lane * 2 + 1];
    float4 b0 = xp[lane * 2], b1 = xp[lane * 2 + 1];

    float ssi = a0.x*a0.x + a0.y*a0.y + a0.z*a0.z + a0.w*a0.w
              + a1.x*a1.x + a1.y*a1.y + a1.z*a1.z + a1.w*a1.w;
    float ssp = b0.x*b0.x + b0.y*b0.y + b0.z*b0.z + b0.w*b0.w
              + b1.x*b1.x + b1.y*b1.y + b1.z*b1.z + b1.w*b1.w;
    float dot = a0.x*b0.x + a0.y*b0.y + a0.z*b0.z + a0.w*b0.w
              + a1.x*b1.x + a1.y*b1.y + a1.z*b1.z + a1.w*b1.w;
#pragma unroll
    for (int off = 32; off; off >>= 1) {
        ssi += __shfl_xor(ssi, off, 64);
        ssp += __shfl_xor(ssp, off, 64);
        dot += __shfl_xor(dot, off, 64);
    }
    const float ni = fmaxf(sqrtf(ssi), 1e-8f);
    const float np = fmaxf(sqrtf(ssp), 1e-8f);
    const float sci = 1.0f / ni, scp = 1.0f / np;

    float va[8] = {a0.x, a0.y, a0.z, a0.w, a1.x, a1.y, a1.z, a1.w};
    float vb[8] = {b0.x, b0.y, b0.z, b0.w, b1.x, b1.y, b1.z, b1.w};
    bf16x8 oi, op;
    float dii = 0.0f, dpp = 0.0f;
#pragma unroll
    for (int t = 0; t < 8; ++t) {
        oi[t] = (bf16_t)(va[t] * sci);
        op[t] = (bf16_t)(vb[t] * scp);
        float fi = (float)oi[t], fp_ = (float)op[t];
        dii += fi * fi;
        dpp += fp_ * fp_;
    }
    *reinterpret_cast<bf16x8*>(xn + (size_t)rowi * DIM + lane * 8) = oi;
    *reinterpret_cast<bf16x8*>(xn + (size_t)rowp * DIM + lane * 8) = op;
#pragma unroll
    for (int off = 32; off; off >>= 1) {
        dii += __shfl_xor(dii, off, 64);
        dpp += __shfl_xor(dpp, off, 64);
    }
    if (lane == 0) {
        const float pv = TEMP_INV * dot * sci * scp;
        pos[rowi] = pv;
        pos[rowp] = pv;          // sim is symmetric: pos[i] == pos[i+N]
        diag[rowi] = TEMP_INV * dii;
        diag[rowp] = TEMP_INV * dpp;
    }
    // zero rowsum (8 entries per block covers 4096 over 512 blocks)
    if (threadIdx.x < 8) rowsum[blockIdx.x * 8 + threadIdx.x] = 0.0f;
}

// ---------------------------------------------------------------------------
// Kernel 2: symmetric sim-GEMM, upper-triangle blocks only (528 of 1024).
// 128x128 tile, 4 waves 2x2, BK=32, mfma 16x16x32 bf16.
//
// T2 XOR-swizzle (both-sides-or-neither, rule #21): the un-swizzled [128][32]
// tile (64B rows) makes every ds_read_b128 an 8-WAY bank conflict. Fix:
//   - global SOURCE slot permuted per thread: slot_g = (t&3) ^ ((t>>3)&3)
//     (global_load_lds dest must stay linear),
//   - fragment READ slot permuted identically: slot_r = q ^ ((l15>>1)&3).
// Post-swizzle: 2 lanes/bank = free (m136). Pure lane permutation ->
// arithmetic bit-identical. (PMC-verified conflict-free: r7 run, 0 conflicts.)
//
// Triple-buffered 1-barrier pipeline: per K-step
//   vmcnt(4) -> s_barrier -> stage(kt+2) -> ds_read(kt) -> 16x MFMA
// One barrier/step; tile kt+2 has 2 full steps of latency cover; vmcnt(4)
// leaves tile kt+1's 4 loads in flight (never drains to 0 in the loop).
// LDS 49KB -> 3 blocks/CU; grid 528 = 2.06/CU fully co-resident.
// Best-measured configuration of the session: 78.3us total (r4).
// ---------------------------------------------------------------------------
__device__ __forceinline__ void load_lds16(const bf16_t* g, bf16_t* l) {
    __builtin_amdgcn_global_load_lds(
        (const __attribute__((address_space(1))) unsigned int*)g,
        (__attribute__((address_space(3))) unsigned int*)l,
        16, 0, 0);
}

__global__ __launch_bounds__(256) void k_simgemm(const bf16_t* __restrict__ xn,
                                                 float* __restrict__ rowsum) {
    __shared__ bf16_t As[3][128 * 32];   // 3 x 8KB
    __shared__ bf16_t Bs[3][128 * 32];   // 3 x 8KB
    __shared__ float  rpA[128];
    __shared__ float  rpB[128];

    // unrank blockIdx.x -> (bm <= bn) upper-triangle pair
    const int t = blockIdx.x;
    int bn = (int)((sqrtf(8.0f * (float)t + 1.0f) - 1.0f) * 0.5f);
    while ((bn * (bn + 1)) / 2 > t) --bn;
    while (((bn + 1) * (bn + 2)) / 2 <= t) ++bn;
    const int bm = t - (bn * (bn + 1)) / 2;
    const bool diagb = (bm == bn);

    const int tid  = threadIdx.x;
    const int lane = tid & 63;
    const int wid  = tid >> 6;
    const int wr   = wid >> 1;
    const int wc   = wid & 1;
    const int q    = lane >> 4;
    const int l15  = lane & 15;

    if (tid < 128) { rpA[tid] = 0.0f; rpB[tid] = 0.0f; }

    // Staging: one K-tile = 128 rows x 32 cols bf16 = 8KB.
    // thread t covers rows (t>>2) and 64+(t>>2); its GLOBAL slot within the
    // row's 64B is XOR-swizzled: ((t&3) ^ ((t>>3)&3)). LDS dest stays linear
    // (t*8 / 2048+t*8) as global_load_lds requires.
    const int slot_g = (tid & 3) ^ ((tid >> 3) & 3);
    const bf16_t* gA = xn + (size_t)(bm * 128 + (tid >> 2)) * DIM + slot_g * 8;
    const bf16_t* gB = xn + (size_t)(bn * 128 + (tid >> 2)) * DIM + slot_g * 8;

    // fragment-read swizzle: same involution, slot_r = q ^ ((l15>>1)&3).
    const int rsw = (q ^ ((l15 >> 1) & 3)) * 8;
    const int arow = (wr * 64 + l15) * 32 + rsw;   // + mt*512
    const int brow = (wc * 64 + l15) * 32 + rsw;   // + nt*512

    f32x4 acc[4][4] = {};

    // prologue: stage K-tiles 0 and 1
    load_lds16(gA,                         &As[0][tid * 8]);
    load_lds16(gA + (size_t)64 * DIM,      &As[0][2048 + tid * 8]);
    load_lds16(gB,                         &Bs[0][tid * 8]);
    load_lds16(gB + (size_t)64 * DIM,      &Bs[0][2048 + tid * 8]);
    load_lds16(gA + 32,                    &As[1][tid * 8]);
    load_lds16(gA + (size_t)64 * DIM + 32, &As[1][2048 + tid * 8]);
    load_lds16(gB + 32,                    &Bs[1][tid * 8]);
    load_lds16(gB + (size_t)64 * DIM + 32, &Bs[1][2048 + tid * 8]);

#pragma unroll
    for (int kt = 0; kt < 16; ++kt) {
        // confirm tile kt resident (own loads), leave tile kt+1's in flight
        if (kt < 15) asm volatile("s_waitcnt vmcnt(4)" ::: "memory");
        else         asm volatile("s_waitcnt vmcnt(0)" ::: "memory");
        __builtin_amdgcn_s_barrier();      // whole tile kt resident; all
                                           // waves' kt-1 reads retired
        __builtin_amdgcn_sched_barrier(0); // pin: nothing floats above

        if (kt + 2 < 16) {                 // stage tile kt+2 (2-step cover)
            const int nb = (kt + 2) % 3;   // == (kt-1)%3, safe per barrier
            const bf16_t* gA2 = gA + (kt + 2) * 32;
            const bf16_t* gB2 = gB + (kt + 2) * 32;
            load_lds16(gA2,                    &As[nb][tid * 8]);
            load_lds16(gA2 + (size_t)64 * DIM, &As[nb][2048 + tid * 8]);
            load_lds16(gB2,                    &Bs[nb][tid * 8]);
            load_lds16(gB2 + (size_t)64 * DIM, &Bs[nb][2048 + tid * 8]);
        }

        const int cb = kt % 3;             // compile-time after unroll
        bf16x8 af[4], bv[4];
#pragma unroll
        for (int mt = 0; mt < 4; ++mt)
            af[mt] = *reinterpret_cast<const bf16x8*>(&As[cb][arow + mt * 512]);
#pragma unroll
        for (int nt = 0; nt < 4; ++nt)
            bv[nt] = *reinterpret_cast<const bf16x8*>(&Bs[cb][brow + nt * 512]);
#pragma unroll
        for (int mt = 0; mt < 4; ++mt)
#pragma unroll
            for (int nt = 0; nt < 4; ++nt)
                acc[mt][nt] = __builtin_amdgcn_mfma_f32_16x16x32_bf16(
                    af[mt], bv[nt], acc[mt][nt], 0, 0, 0);
    }

    // Epilogue. C/D: row = wr*64+mt*16+q*4+r, col = wc*64+nt*16+l15.
    float colacc[4] = {0.0f, 0.0f, 0.0f, 0.0f};
#pragma unroll
    for (int mt = 0; mt < 4; ++mt) {
        float rowp[4] = {0.0f, 0.0f, 0.0f, 0.0f};
#pragma unroll
        for (int nt = 0; nt < 4; ++nt)
#pragma unroll
            for (int r = 0; r < 4; ++r) {
                float e = __expf(TEMP_INV * acc[mt][nt][r]);
                rowp[r] += e;
                colacc[nt] += e;
            }
#pragma unroll
        for (int r = 0; r < 4; ++r) {
            float p = rowp[r];
            p += __shfl_xor(p, 1, 64);
            p += __shfl_xor(p, 2, 64);
            p += __shfl_xor(p, 4, 64);
            p += __shfl_xor(p, 8, 64);
            if (l15 == 0) atomicAdd(&rpA[wr * 64 + mt * 16 + q * 4 + r], p);
        }
    }
    if (!diagb) {
#pragma unroll
        for (int nt = 0; nt < 4; ++nt) {
            float c = colacc[nt];
            c += __shfl_xor(c, 16, 64);
            c += __shfl_xor(c, 32, 64);
            if (q == 0) atomicAdd(&rpB[wc * 64 + nt * 16 + l15], c);
        }
    }
    __syncthreads();
    if (tid < 128) {
        atomicAdd(&rowsum[bm * 128 + tid], rpA[tid]);
    } else if (!diagb) {
        atomicAdd(&rowsum[bn * 128 + (tid - 128)], rpB[tid - 128]);
    }
}

// ---------------------------------------------------------------------------
// Kernel 3: loss = mean_i( log(S_i - exp(diag_i)) - pos_i )
// float4-vectorized single block (4 unrolled rounds of 3x16B loads).
// ---------------------------------------------------------------------------
__global__ __launch_bounds__(256) void k_finalize(const float* __restrict__ rowsum,
                                                  const float* __restrict__ pos,
                                                  const float* __restrict__ diag,
                                                  float* __restrict__ out) {
    __shared__ float red[256];
    const float4* rs4 = reinterpret_cast<const float4*>(rowsum);
    const float4* ps4 = reinterpret_cast<const float4*>(pos);
    const float4* dg4 = reinterpret_cast<const float4*>(diag);
    float s = 0.0f;
#pragma unroll
    for (int it = 0; it < 4; ++it) {
        const int i = it * 256 + threadIdx.x;   // 1024 float4 = 4096 floats
        float4 r = rs4[i];
        float4 p = ps4[i];
        float4 d = dg4[i];
        s += __logf(r.x - __expf(d.x)) - p.x;
        s += __logf(r.y - __expf(d.y)) - p.y;
        s += __logf(r.z - __expf(d.z)) - p.z;
        s += __logf(r.w - __expf(d.w)) - p.w;
    }
    red[threadIdx.x] = s;
    __syncthreads();
    for (int st = 128; st; st >>= 1) {
        if (threadIdx.x < st) red[threadIdx.x] += red[threadIdx.x + st];
        __syncthreads();
    }
    if (threadIdx.x == 0) out[0] = red[0] / (float)N2;
}

// ---------------------------------------------------------------------------
extern "C" void kernel_launch(void* const* d_in, const int* in_sizes, int n_in,
                              void* d_out, int out_size, void* d_ws, size_t ws_size,
                              hipStream_t stream) {
    (void)in_sizes; (void)n_in; (void)out_size; (void)ws_size;
    const float* x = (const float*)d_in[0];
    float* out = (float*)d_out;

    char* ws = (char*)d_ws;
    bf16_t* xn     = (bf16_t*)ws;                          // 4 MB
    float*  rowsum = (float*)(ws + (size_t)N2 * DIM * 2);  // 16 KB
    float*  pos    = rowsum + N2;
    float*  diag   = pos + N2;

    k_prep<<<512, 256, 0, stream>>>(x, xn, pos, diag, rowsum);
    k_simgemm<<<528, 256, 0, stream>>>(xn, rowsum);
    k_finalize<<<1, 256, 0, stream>>>(rowsum, pos, diag, out);
}